// Round 28
// baseline (169.297 us; speedup 1.0000x reference)
//
#include <hip/hip_runtime.h>
#include <hip/hip_bf16.h>
#include <math.h>

// Problem constants
#define B_   8
#define N_   2000
#define C_   512
#define H_   8
#define W_   5
#define SR_  2
#define M_   1000      // N/SR
#define HD_  64        // C/H
#define KK_  512       // shared inner dim of every projection
#define RP_  8192      // padded row count for pooled path (8000 -> 8192)
#define NPAD_ 16384    // padded row count for q/kv buffers
#define LN_EPS_ 1e-5f
#define SCALE_  0.125f             // hd^-0.5
#define QSC_    0.18033688011112042f  // SCALE_ * log2(e): QK scores in log2 domain

// attention tiling (32x32 swapped-operand structure, 8-wave blocks) -- r20/r24 proven config
#define TQ_   256      // q rows per block: 8 waves x 32 queries
#define NCH_  8        // chunks per (b,h)
#define LT_   5        // local tiles per chunk
#define KSTR2 72       // LDS row stride in bf16: 144B rows, single b128 access, 0 conflicts

typedef __attribute__((ext_vector_type(8))) short bf16x8;
typedef __attribute__((ext_vector_type(4))) short short4v;
typedef __attribute__((ext_vector_type(4))) float f32x4;
typedef __attribute__((ext_vector_type(16))) float f32x16;
#define MFMA16(a,b,c) __builtin_amdgcn_mfma_f32_16x16x32_bf16(a,b,c,0,0,0)
#define MFMA32(a,b,c) __builtin_amdgcn_mfma_f32_32x32x16_bf16(a,b,c,0,0,0)

// LDS-only barrier (r27: neutral vs __syncthreads, kept -- never worse).
__device__ __forceinline__ void lds_barrier() {
  asm volatile("s_waitcnt lgkmcnt(0)" ::: "memory");
  __builtin_amdgcn_s_barrier();
}

__device__ __forceinline__ short f2bf(float f) {
  unsigned u = __float_as_uint(f);
  u += 0x7FFFu + ((u >> 16) & 1u);
  return (short)(u >> 16);
}
__device__ __forceinline__ uint2 pack4bf(float4 v) {
  unsigned a = ((unsigned)(unsigned short)f2bf(v.x)) | (((unsigned)(unsigned short)f2bf(v.y)) << 16);
  unsigned b = ((unsigned)(unsigned short)f2bf(v.z)) | (((unsigned)(unsigned short)f2bf(v.w)) << 16);
  return make_uint2(a, b);
}

__device__ __forceinline__ float wave_sum(float v) {
#pragma unroll
  for (int o = 32; o > 0; o >>= 1) v += __shfl_xor(v, o);
  return v;
}

__device__ __forceinline__ void gl_lds16(const void* g, void* l) {
  __builtin_amdgcn_global_load_lds(
      (const __attribute__((address_space(1))) void*)g,
      (__attribute__((address_space(3))) void*)l, 16, 0, 0);
}

// XCD-aware decode for a ROWS x NBX tile grid launched 1D.
// Bijective (exact tail handling for ROWS % 8 != 0). NBX must equal O/128.
template<int ROWS, int NBX>
__device__ __forceinline__ void xcd_decode(int b, int& row, int& bx) {
  constexpr int GROUP = 8 * NBX;
  constexpr int FULL  = (ROWS / 8) * GROUP;
  constexpr int REM   = ROWS % 8;
  if (b < FULL) {
    row = 8 * (b / GROUP) + (b & 7);
    bx  = (b % GROUP) >> 3;
  } else {
    int b2 = b - FULL;
    row = (ROWS - REM) + (REM ? b2 % (REM ? REM : 1) : 0);
    bx  = REM ? b2 / REM : 0;
  }
}

// ---------------- fused fp32 -> bf16 convert for ALL weights (one launch) ----------------
__global__ __launch_bounds__(256) void cvt_all(const float* __restrict__ Wq,
                                               const float* __restrict__ Wkv,
                                               const float* __restrict__ Wc,
                                               const float* __restrict__ Wp,
                                               short* __restrict__ Wqkvb,
                                               short* __restrict__ Wcb,
                                               short* __restrict__ Wpb) {
  int i = blockIdx.x * 256 + threadIdx.x;      // item = 8 elems
  const int nq = 512*512/8, nkv = 1024*512/8, nc = 512*512/8, np = 512*512/8;
  if (i >= nq + nkv + nc + np) return;
  const float* src; short* dst; int off;
  if (i < nq)                { src = Wq;  dst = Wqkvb;             off = i; }
  else if (i < nq + nkv)     { src = Wkv; dst = Wqkvb + 512*512;   off = i - nq; }
  else if (i < nq + nkv + nc){ src = Wc;  dst = Wcb;               off = i - nq - nkv; }
  else                       { src = Wp;  dst = Wpb;               off = i - nq - nkv - nc; }
  float4 a = reinterpret_cast<const float4*>(src)[off * 2];
  float4 b = reinterpret_cast<const float4*>(src)[off * 2 + 1];
  uint2 pa = pack4bf(a), pb = pack4bf(b);
  reinterpret_cast<uint4*>(dst)[off] = make_uint4(pa.x, pa.y, pb.x, pb.y);
}

// ---------------- fused x->bf16 convert + pair-mean pool ----------------
__global__ __launch_bounds__(256) void cvt_pool(const float* __restrict__ X,
                                                short* __restrict__ Xb,
                                                short* __restrict__ Xp) {
  int idx = blockIdx.x * 256 + threadIdx.x;
  const int total = B_ * M_ * (C_ / 8);
  if (idx >= total) return;
  int row = idx / (C_ / 8);     // pooled row
  int c8  = idx % (C_ / 8);
  int b = row / M_, m = row % M_;
  size_t r0 = ((size_t)b * N_ + 2 * m) * C_ + c8 * 8;
  size_t r1 = r0 + C_;
  float4 a0 = *(const float4*)(X + r0), a1 = *(const float4*)(X + r0 + 4);
  float4 b0 = *(const float4*)(X + r1), b1 = *(const float4*)(X + r1 + 4);
  uint2 pa0 = pack4bf(a0), pa1 = pack4bf(a1);
  uint2 pb0 = pack4bf(b0), pb1 = pack4bf(b1);
  *(uint4*)(Xb + r0) = make_uint4(pa0.x, pa0.y, pa1.x, pa1.y);
  *(uint4*)(Xb + r1) = make_uint4(pb0.x, pb0.y, pb1.x, pb1.y);
  float4 s0, s1;
  s0.x = 0.5f * (a0.x + b0.x); s0.y = 0.5f * (a0.y + b0.y);
  s0.z = 0.5f * (a0.z + b0.z); s0.w = 0.5f * (a0.w + b0.w);
  s1.x = 0.5f * (a1.x + b1.x); s1.y = 0.5f * (a1.y + b1.y);
  s1.z = 0.5f * (a1.z + b1.z); s1.w = 0.5f * (a1.w + b1.w);
  uint2 q0 = pack4bf(s0), q1 = pack4bf(s1);
  *(uint4*)(Xp + (size_t)row * C_ + c8 * 8) = make_uint4(q0.x, q0.y, q1.x, q1.y);
}

// ---------------- shared GEMM core: 128x128 tile, BK=64, K=512 ----------------
// 8 K-steps x 2 barriers (halved from BK=32's 16 steps).
// Full XOR bank swizzle, m104-compliant: LDS linear for global_load_lds
// (dest wave-uniform; lanes fill 8 rows x 8 slots of 16B); the GLOBAL source
// slot is pre-swizzled (slot ^ row&7) and the fragment read applies the same
// involution ((ks*4+g) ^ (c0&7)). 16 read lanes -> 8 slot groups x 2 = 2-way (free).
__device__ __forceinline__ void gemm_core(const short* __restrict__ A,
                                          const short* __restrict__ Bm,
                                          long r0, long o0,
                                          short* As, short* Bs,
                                          f32x4 (&acc)[4][4]) {
  const int tid  = threadIdx.x;
  const int w    = tid >> 6;
  const int lane = tid & 63;
  const int g    = lane >> 4;
  const int c0   = lane & 15;
  const int wr   = w >> 1;
  const int wc   = w & 1;
  const int lrow  = lane >> 3;          // 0..7 within the wave's 8-row group
  const int sslot = (lane & 7) ^ lrow;  // swizzled global source slot
  const int rsw   = c0 & 7;             // read-side involution

  for (int kk = 0; kk < 8; ++kk) {
    __syncthreads();
#pragma unroll
    for (int i = 0; i < 4; ++i) {
      const int baser = i * 32 + w * 8;     // wave-uniform row base (8 rows/wave/issue)
      gl_lds16(A  + (r0 + baser + lrow) * KK_ + kk * 64 + sslot * 8, &As[baser * 64]);
      gl_lds16(Bm + (o0 + baser + lrow) * KK_ + kk * 64 + sslot * 8, &Bs[baser * 64]);
    }
    __syncthreads();
#pragma unroll
    for (int ks = 0; ks < 2; ++ks) {
      bf16x8 a[4], b[4];
#pragma unroll
      for (int m = 0; m < 4; ++m) {
        const int row = wr * 64 + m * 16 + c0;
        a[m] = *(const bf16x8*)&As[row * 64 + (((ks * 4 + g) ^ rsw) * 8)];
      }
#pragma unroll
      for (int n = 0; n < 4; ++n) {
        const int row = wc * 64 + n * 16 + c0;
        b[n] = *(const bf16x8*)&Bs[row * 64 + (((ks * 4 + g) ^ rsw) * 8)];
      }
#pragma unroll
      for (int m = 0; m < 4; ++m)
#pragma unroll
        for (int n = 0; n < 4; ++n) acc[m][n] = MFMA16(a[m], b[n], acc[m][n]);
    }
  }
}

// ---------------- MFMA bf16 GEMM: Y = X(R,512) * W(O,512)^T + b ----------------
template<int OUT_BF16, int ROWS, int NBX>
__global__ __launch_bounds__(256) void gemm_mfma(const short* __restrict__ A,
                                                 const short* __restrict__ Bm,
                                                 const float* __restrict__ bias,
                                                 void* __restrict__ Yv,
                                                 int O, float oscale) {
  __shared__ short As[128 * 64];
  __shared__ short Bs[128 * 64];
  const int tid  = threadIdx.x;
  const int w    = tid >> 6;
  const int lane = tid & 63;
  const int g    = lane >> 4;
  const int c0   = lane & 15;
  const int wr   = w >> 1;
  const int wc   = w & 1;
  int rowb, bx;
  xcd_decode<ROWS, NBX>(blockIdx.x, rowb, bx);
  const long r0 = (long)rowb * 128;
  const long o0 = (long)bx * 128;

  f32x4 acc[4][4];
#pragma unroll
  for (int m = 0; m < 4; ++m)
#pragma unroll
    for (int n = 0; n < 4; ++n) acc[m][n] = (f32x4){0.f, 0.f, 0.f, 0.f};

  gemm_core(A, Bm, r0, o0, As, Bs, acc);

#pragma unroll
  for (int m = 0; m < 4; ++m) {
    long row = r0 + wr * 64 + m * 16 + g * 4;
#pragma unroll
    for (int n = 0; n < 4; ++n) {
      long col = o0 + wc * 64 + n * 16 + c0;
      float bv = bias[col];
#pragma unroll
      for (int r = 0; r < 4; ++r) {
        float v = (acc[m][n][r] + bv) * oscale;
        if (OUT_BF16) ((short*)Yv)[(row + r) * O + col] = f2bf(v);
        else          ((float*)Yv)[(row + r) * O + col] = v;
      }
    }
  }
}

// ---------------- fused launch: q+kv projection (1500 blocks) + pooled Wc GEMM (256 blocks) ----------------
__global__ __launch_bounds__(256) void gemm_qkv_wc(const short* __restrict__ xb,
                                                   const short* __restrict__ Wqkvb,
                                                   const float* __restrict__ bq,
                                                   const float* __restrict__ bkv,
                                                   short* __restrict__ Yq,
                                                   short* __restrict__ Ykv,
                                                   const short* __restrict__ xpb,
                                                   const short* __restrict__ Wcb,
                                                   const float* __restrict__ bc,
                                                   float* __restrict__ xc) {
  __shared__ short As[128 * 64];
  __shared__ short Bs[128 * 64];
  const int tid  = threadIdx.x;
  const int w    = tid >> 6;
  const int lane = tid & 63;
  const int g    = lane >> 4;
  const int c0   = lane & 15;
  const int wr   = w >> 1;
  const int wc   = w & 1;

  f32x4 acc[4][4];
#pragma unroll
  for (int m = 0; m < 4; ++m)
#pragma unroll
    for (int n = 0; n < 4; ++n) acc[m][n] = (f32x4){0.f, 0.f, 0.f, 0.f};

  const int blk = blockIdx.x;
  if (blk < 1500) {                       // qkv: 125 rows x 12 cols, XCD-swizzled
    int rowb, bx;
    xcd_decode<125, 12>(blk, rowb, bx);
    const long r0 = (long)rowb * 128;
    const long o0 = (long)bx * 128;
    gemm_core(xb, Wqkvb, r0, o0, As, Bs, acc);
    const bool isq = (bx < 4);
#pragma unroll
    for (int m = 0; m < 4; ++m) {
      long row = r0 + wr * 64 + m * 16 + g * 4;
#pragma unroll
      for (int n = 0; n < 4; ++n) {
        long col = o0 + wc * 64 + n * 16 + c0;
        if (isq) {
          float bv = bq[col];
#pragma unroll
          for (int r = 0; r < 4; ++r)
            Yq[(row + r) * 512 + col] = f2bf((acc[m][n][r] + bv) * QSC_);
        } else {
          long ck = col - 512;
          float bv = bkv[ck];
#pragma unroll
          for (int r = 0; r < 4; ++r)
            Ykv[(row + r) * 1024 + ck] = f2bf(acc[m][n][r] + bv);
        }
      }
    }
  } else {                                // pooled Wc: 64 rows x 4 cols, XCD-swizzled
    int rowb, bx;
    xcd_decode<64, 4>(blk - 1500, rowb, bx);
    const long r0 = (long)rowb * 128;
    const long o0 = (long)bx * 128;
    gemm_core(xpb, Wcb, r0, o0, As, Bs, acc);
#pragma unroll
    for (int m = 0; m < 4; ++m) {
      long row = r0 + wr * 64 + m * 16 + g * 4;
#pragma unroll
      for (int n = 0; n < 4; ++n) {
        long col = o0 + wc * 64 + n * 16 + c0;
        float bv = bc[col];
#pragma unroll
        for (int r = 0; r < 4; ++r)
          xc[(row + r) * 512 + col] = acc[m][n][r] + bv;
      }
    }
  }
}

// LayerNorm + exact GELU: fp32 in -> bf16 out, rows of 512
__global__ __launch_bounds__(256) void ln_gelu(const float* __restrict__ Xc,
                                               short* __restrict__ Xo,
                                               const float* __restrict__ gam,
                                               const float* __restrict__ bet) {
  const int row = blockIdx.x;
  const float* p = Xc + (size_t)row * C_;
  const int t = threadIdx.x;
  float v0 = p[t], v1 = p[t + 256];
  float s  = wave_sum(v0 + v1);
  float ss = wave_sum(v0 * v0 + v1 * v1);
  __shared__ float rs[4], rss[4];
  const int w = t >> 6, lane = t & 63;
  if (lane == 0) { rs[w] = s; rss[w] = ss; }
  __syncthreads();
  float ts  = rs[0] + rs[1] + rs[2] + rs[3];
  float tss = rss[0] + rss[1] + rss[2] + rss[3];
  float mean = ts * (1.0f / C_);
  float var  = tss * (1.0f / C_) - mean * mean;
  float rstd = rsqrtf(var + LN_EPS_);
  float u0 = (v0 - mean) * rstd * gam[t]       + bet[t];
  float u1 = (v1 - mean) * rstd * gam[t + 256] + bet[t + 256];
  Xo[(size_t)row * C_ + t]       = f2bf(u0 * 0.5f * (1.0f + erff(u0 * 0.70710678118654752f)));
  Xo[(size_t)row * C_ + t + 256] = f2bf(u1 * 0.5f * (1.0f + erff(u1 * 0.70710678118654752f)));
}

// ---------------- 32x32 swapped-operand MFMA flash attention (r24 proven form) ----------------
// Fixed-reference softmax (m == 0), VALU l-sum (4-way partials + 1 shfl).
// MODE: 0 pooled, 1 local window, 2 pooled tail.
template<int MODE>
__device__ __forceinline__ void tile32(const short* Ksb, const short* Vtb,
                                       const bf16x8 qf[4],
                                       float& l_c, f32x16* o,
                                       int c, int hi, int koff)
{
  f32x16 sblk[2];
  __builtin_amdgcn_s_setprio(1);
#pragma unroll
  for (int kb = 0; kb < 2; ++kb) {
    f32x16 acc = {};
#pragma unroll
    for (int sl = 0; sl < 4; ++sl) {
      bf16x8 kf = *(const bf16x8*)&Ksb[(kb*32 + c)*KSTR2 + sl*16 + hi*8];
      acc = MFMA32(kf, qf[sl], acc);
    }
    sblk[kb] = acc;
  }
  __builtin_amdgcn_s_setprio(0);

  if (MODE == 1) {
#pragma unroll
    for (int kb = 0; kb < 2; ++kb)
#pragma unroll
      for (int r = 0; r < 16; ++r) {
        int ku = koff + kb*32 + ((r & 3) + 8*(r >> 2));
        if ((unsigned)ku >= 5u) sblk[kb][r] = -3.0e38f;
      }
  }
  if (MODE == 2) {
#pragma unroll
    for (int r = 4; r < 16; ++r) sblk[1][r] = -3.0e38f;   // keys 1000..1023
  }

  float rs4[4] = {0.f, 0.f, 0.f, 0.f};
  int dw[2][8];
#pragma unroll
  for (int kb = 0; kb < 2; ++kb)
#pragma unroll
    for (int i = 0; i < 8; ++i) {
      float p0 = exp2f(sblk[kb][2*i]);
      float p1 = exp2f(sblk[kb][2*i + 1]);
      rs4[i & 3] += p0 + p1;
      int d;
      asm("v_cvt_pk_bf16_f32 %0, %1, %2" : "=v"(d) : "v"(p0), "v"(p1));
      dw[kb][i] = d;
    }
  float rs = (rs4[0] + rs4[1]) + (rs4[2] + rs4[3]);
  rs += __shfl_xor(rs, 32);
  l_c += rs;

  bf16x8 pfrag[2][2];
#pragma unroll
  for (int kb = 0; kb < 2; ++kb)
#pragma unroll
    for (int kp = 0; kp < 2; ++kp) {
      union { int i[4]; bf16x8 v; } u;
      u.i[0] = dw[kb][kp*4 + 0];
      u.i[1] = dw[kb][kp*4 + 1];
      u.i[2] = dw[kb][kp*4 + 2];
      u.i[3] = dw[kb][kp*4 + 3];
      pfrag[kb][kp] = u.v;
    }

  __builtin_amdgcn_s_setprio(1);
#pragma unroll
  for (int db = 0; db < 2; ++db)
#pragma unroll
    for (int kb = 0; kb < 2; ++kb)
#pragma unroll
      for (int kp = 0; kp < 2; ++kp) {
        bf16x8 vf = *(const bf16x8*)&Vtb[(db*32 + c)*KSTR2 + kb*32 + kp*16 + hi*8];
        o[db] = MFMA32(vf, pfrag[kb][kp], o[db]);
      }
  __builtin_amdgcn_s_setprio(0);
}

// Block = 512 thr (8 waves x 32 q = 256 q). 8 chunks per (b,h). Grid 512.
// Staging split: waves 0-3 load K, waves 4-7 load V. LDS-only barriers.
__global__ __launch_bounds__(512, 4) void attn_mfma32(const short* __restrict__ Q,
                                                      const short* __restrict__ KV,
                                                      const short* __restrict__ KVP,
                                                      short* __restrict__ Oa) {
  __shared__ __align__(16) short Ks[2][64 * KSTR2];
  __shared__ __align__(16) short Vt[2][64 * KSTR2];

  const int bid   = blockIdx.x;
  const int bh    = bid & 63;          // XCD-aware decode
  const int chunk = bid >> 6;
  const int b     = bh >> 3;
  const int h     = bh & 7;
  const int n0    = chunk * TQ_;
  const int tid  = threadIdx.x;
  const int wq   = tid >> 6;           // 0..7
  const int lane = tid & 63;
  const int c    = lane & 31;
  const int hi   = lane >> 5;

  const int qabs = n0 + wq * 32 + c;   // absolute query index, <= 2047
  const size_t qrow = (size_t)(b * N_ + qabs) * C_ + h * HD_;
  bf16x8 qf[4];
#pragma unroll
  for (int sl = 0; sl < 4; ++sl) qf[sl] = *(const bf16x8*)(Q + qrow + sl*16 + hi*8);

  const int qlo = (qabs / 5) * 5;
  const int klo = (n0 / 5) * 5;
  const int wlo = ((n0 + wq*32) / 5) * 5;
  const int whi = ((n0 + wq*32 + 31) / 5) * 5 + 5;

  const bool isK = (tid < 256);
  const int u    = tid & 255;
  const int kkey = u >> 3, kdq = u & 7;
  const int vkp  = u & 31, vdq = (u >> 5) & 7;
  const int svkp = (vkp & ~6) | ((vkp & 2) << 1) | ((vkp & 4) >> 1);
  bf16x8 r0v, r1v;

  auto issue = [&](const short* pb_) {
    if (isK) {
      r0v = *(const bf16x8*)(pb_ + (size_t)kkey        * (2*C_) + h*HD_ + kdq*8);
      r1v = *(const bf16x8*)(pb_ + (size_t)(kkey + 32) * (2*C_) + h*HD_ + kdq*8);
    } else {
      r0v = *(const bf16x8*)(pb_ + (size_t)(2*vkp)     * (2*C_) + C_ + h*HD_ + vdq*8);
      r1v = *(const bf16x8*)(pb_ + (size_t)(2*vkp + 1) * (2*C_) + C_ + h*HD_ + vdq*8);
    }
  };
  auto write = [&](int buf) {
    if (isK) {
      *(bf16x8*)&Ks[buf][kkey * KSTR2 + kdq * 8]        = r0v;
      *(bf16x8*)&Ks[buf][(kkey + 32) * KSTR2 + kdq * 8] = r1v;
    } else {
#pragma unroll
      for (int e = 0; e < 8; ++e) {
        unsigned wv = ((unsigned)(unsigned short)r0v[e]) | (((unsigned)(unsigned short)r1v[e]) << 16);
        *(unsigned*)&Vt[buf][(vdq*8 + e) * KSTR2 + 2*svkp] = wv;
      }
    }
  };

  const short* kvloc = KV  + (size_t)(b * N_ + klo) * (2*C_);
  const short* kvp_b = KVP + (size_t)(b * M_)       * (2*C_);

  float l_c = 0.f;
  f32x16 o[2];
  o[0] = (f32x16){}; o[1] = (f32x16){};

  issue(kvloc);
  write(0);
  lds_barrier();
  int cur = 0;

#pragma unroll 1
  for (int t = 0; t < LT_; ++t) {          // local tiles (absolute keys klo+64t)
    const short* nxt = (t < LT_ - 1) ? kvloc + (size_t)(t + 1) * 64 * (2*C_) : kvp_b;
    issue(nxt);
    const int base = klo + t * 64;
    if (base < whi && base + 64 > wlo)
      tile32<1>(Ks[cur], Vt[cur], qf, l_c, o, c, hi, base + 4*hi - qlo);
    write(cur ^ 1);
    lds_barrier();
    cur ^= 1;
  }
#pragma unroll 1
  for (int t = 0; t < 15; ++t) {           // pooled tiles 0..14 (prefetch 1..15)
    issue(kvp_b + (size_t)(t + 1) * 64 * (2*C_));
    tile32<0>(Ks[cur], Vt[cur], qf, l_c, o, c, hi, 0);
    write(cur ^ 1);
    lds_barrier();
    cur ^= 1;
  }
  tile32<2>(Ks[cur], Vt[cur], qf, l_c, o, c, hi, 0);  // pooled tail (40 keys)

  if (qabs < N_) {
    float inv = 1.0f / l_c;
    short* orow = Oa + ((size_t)(b * N_ + qabs)) * C_ + h * HD_;
#pragma unroll
    for (int db = 0; db < 2; ++db)
#pragma unroll
      for (int rq = 0; rq < 4; ++rq) {
        short4v sv;
#pragma unroll
        for (int i = 0; i < 4; ++i) sv[i] = f2bf(o[db][rq*4 + i] * inv);
        *(short4v*)(orow + db*32 + rq*8 + 4*hi) = sv;
      }
  }
}

extern "C" void kernel_launch(void* const* d_in, const int* in_sizes, int n_in,
                              void* d_out, int out_size, void* d_ws, size_t ws_size,
                              hipStream_t stream) {
  const float* x   = (const float*)d_in[0];
  const float* Wq  = (const float*)d_in[1];
  const float* bq  = (const float*)d_in[2];
  const float* Wkv = (const float*)d_in[3];
  const float* bkv = (const float*)d_in[4];
  const float* Wc  = (const float*)d_in[5];
  const float* bc  = (const float*)d_in[6];
  const float* lng = (const float*)d_in[7];
  const float* lnb = (const float*)d_in[8];
  const float* Wp  = (const float*)d_in[9];
  const float* bp  = (const float*)d_in[10];
  float* out = (float*)d_out;

  // workspace layout: fp32 region first, then bf16 regions (all 16B aligned)
  float* xc   = (float*)d_ws;                         // RP_*512 fp32
  short* sb   = (short*)(xc + (size_t)RP_ * 512);
  short* xb    = sb;                                  // 16000*512
  short* qb    = xb   + (size_t)16000 * 512;          // NPAD_*512 (pre-scaled, log2-domain)
  short* kvb   = qb   + (size_t)NPAD_ * 512;          // NPAD_*1024
  short* xpb   = kvb  + (size_t)NPAD_ * 1024;         // RP_*512
  short* xcb   = xpb  + (size_t)RP_ * 512;            // RP_*512
  short* kvpb  = xcb  + (size_t)RP_ * 512;            // RP_*1024
  short* aoutb = kvpb + (size_t)RP_ * 1024;           // 16000*512
  short* Wqkvb = aoutb + (size_t)16000 * 512;         // 1536*512 (q rows 0..511, kv rows 512..1535)
  short* Wcb   = Wqkvb + (size_t)1536 * 512;          // 512*512
  short* Wpb   = Wcb  + (size_t)512 * 512;            // 512*512

  dim3 blk(256);

  // converts + fused pool (weights in ONE launch)
  cvt_pool<<<dim3((B_*M_*(C_/8) + 255)/256), blk, 0, stream>>>(x, xb, xpb);
  cvt_all<<<dim3((2560*512/8 + 255)/256), blk, 0, stream>>>(Wq, Wkv, Wc, Wp, Wqkvb, Wcb, Wpb);

  // fused launch: q+kv projection + pooled Wc GEMM (both XCD-swizzled, BK=64 core)
  gemm_qkv_wc<<<dim3(1756), blk, 0, stream>>>(xb, Wqkvb, bq, bkv, qb, kvb,
                                              xpb, Wcb, bc, xc);

  // pooled pre-path tail
  ln_gelu<<<dim3(B_ * M_), blk, 0, stream>>>(xc, xcb, lng, lnb);
  gemm_mfma<1, 64, 8><<<dim3(512), blk, 0, stream>>>(xcb, Wqkvb + 512*512, bkv, kvpb, 2*C_, 1.0f);

  // fused attention: 8-wave blocks, fixed-reference softmax, LDS-only barriers
  attn_mfma32<<<dim3(64 * NCH_), dim3(512), 0, stream>>>(qb, kvb, kvpb, aoutb);

  // output projection (fp32 out, XCD-swizzled; O=512 -> 4 column tiles)
  gemm_mfma<0, 125, 4><<<dim3(500), blk, 0, stream>>>(aoutb, Wpb, bp, out, C_, 1.0f);
}

// Round 29
// 162.053 us; speedup vs baseline: 1.0447x; 1.0447x over previous
//
#include <hip/hip_runtime.h>
#include <hip/hip_bf16.h>
#include <math.h>

// Problem constants
#define B_   8
#define N_   2000
#define C_   512
#define H_   8
#define W_   5
#define SR_  2
#define M_   1000      // N/SR
#define HD_  64        // C/H
#define KK_  512       // shared inner dim of every projection
#define RP_  8192      // padded row count for pooled path (8000 -> 8192)
#define NPAD_ 16384    // padded row count for q/kv buffers
#define LN_EPS_ 1e-5f
#define SCALE_  0.125f             // hd^-0.5
#define QSC_    0.18033688011112042f  // SCALE_ * log2(e): QK scores in log2 domain

// attention tiling (32x32 swapped-operand structure, 8-wave blocks) -- r20/r24 proven config
#define TQ_   256      // q rows per block: 8 waves x 32 queries
#define NCH_  8        // chunks per (b,h)
#define LT_   5        // local tiles per chunk
#define KSTR2 72       // LDS row stride in bf16: 144B rows, single b128 access, 0 conflicts

typedef __attribute__((ext_vector_type(8))) short bf16x8;
typedef __attribute__((ext_vector_type(4))) short short4v;
typedef __attribute__((ext_vector_type(4))) float f32x4;
typedef __attribute__((ext_vector_type(16))) float f32x16;
#define MFMA16(a,b,c) __builtin_amdgcn_mfma_f32_16x16x32_bf16(a,b,c,0,0,0)
#define MFMA32(a,b,c) __builtin_amdgcn_mfma_f32_32x32x16_bf16(a,b,c,0,0,0)

// LDS-only barrier (r27: neutral vs __syncthreads, kept -- never worse).
__device__ __forceinline__ void lds_barrier() {
  asm volatile("s_waitcnt lgkmcnt(0)" ::: "memory");
  __builtin_amdgcn_s_barrier();
}

__device__ __forceinline__ short f2bf(float f) {
  unsigned u = __float_as_uint(f);
  u += 0x7FFFu + ((u >> 16) & 1u);
  return (short)(u >> 16);
}
__device__ __forceinline__ uint2 pack4bf(float4 v) {
  unsigned a = ((unsigned)(unsigned short)f2bf(v.x)) | (((unsigned)(unsigned short)f2bf(v.y)) << 16);
  unsigned b = ((unsigned)(unsigned short)f2bf(v.z)) | (((unsigned)(unsigned short)f2bf(v.w)) << 16);
  return make_uint2(a, b);
}

__device__ __forceinline__ float wave_sum(float v) {
#pragma unroll
  for (int o = 32; o > 0; o >>= 1) v += __shfl_xor(v, o);
  return v;
}

__device__ __forceinline__ void gl_lds16(const void* g, void* l) {
  __builtin_amdgcn_global_load_lds(
      (const __attribute__((address_space(1))) void*)g,
      (__attribute__((address_space(3))) void*)l, 16, 0, 0);
}

// XCD-aware decode for a ROWS x NBX tile grid launched 1D.
// Bijective (exact tail handling for ROWS % 8 != 0). NBX must equal O/128.
template<int ROWS, int NBX>
__device__ __forceinline__ void xcd_decode(int b, int& row, int& bx) {
  constexpr int GROUP = 8 * NBX;
  constexpr int FULL  = (ROWS / 8) * GROUP;
  constexpr int REM   = ROWS % 8;
  if (b < FULL) {
    row = 8 * (b / GROUP) + (b & 7);
    bx  = (b % GROUP) >> 3;
  } else {
    int b2 = b - FULL;
    row = (ROWS - REM) + (REM ? b2 % (REM ? REM : 1) : 0);
    bx  = REM ? b2 / REM : 0;
  }
}

// ---------------- fused fp32 -> bf16 convert for ALL weights (one launch) ----------------
__global__ __launch_bounds__(256) void cvt_all(const float* __restrict__ Wq,
                                               const float* __restrict__ Wkv,
                                               const float* __restrict__ Wc,
                                               const float* __restrict__ Wp,
                                               short* __restrict__ Wqkvb,
                                               short* __restrict__ Wcb,
                                               short* __restrict__ Wpb) {
  int i = blockIdx.x * 256 + threadIdx.x;      // item = 8 elems
  const int nq = 512*512/8, nkv = 1024*512/8, nc = 512*512/8, np = 512*512/8;
  if (i >= nq + nkv + nc + np) return;
  const float* src; short* dst; int off;
  if (i < nq)                { src = Wq;  dst = Wqkvb;             off = i; }
  else if (i < nq + nkv)     { src = Wkv; dst = Wqkvb + 512*512;   off = i - nq; }
  else if (i < nq + nkv + nc){ src = Wc;  dst = Wcb;               off = i - nq - nkv; }
  else                       { src = Wp;  dst = Wpb;               off = i - nq - nkv - nc; }
  float4 a = reinterpret_cast<const float4*>(src)[off * 2];
  float4 b = reinterpret_cast<const float4*>(src)[off * 2 + 1];
  uint2 pa = pack4bf(a), pb = pack4bf(b);
  reinterpret_cast<uint4*>(dst)[off] = make_uint4(pa.x, pa.y, pb.x, pb.y);
}

// ---------------- fused x->bf16 convert + pair-mean pool ----------------
__global__ __launch_bounds__(256) void cvt_pool(const float* __restrict__ X,
                                                short* __restrict__ Xb,
                                                short* __restrict__ Xp) {
  int idx = blockIdx.x * 256 + threadIdx.x;
  const int total = B_ * M_ * (C_ / 8);
  if (idx >= total) return;
  int row = idx / (C_ / 8);     // pooled row
  int c8  = idx % (C_ / 8);
  int b = row / M_, m = row % M_;
  size_t r0 = ((size_t)b * N_ + 2 * m) * C_ + c8 * 8;
  size_t r1 = r0 + C_;
  float4 a0 = *(const float4*)(X + r0), a1 = *(const float4*)(X + r0 + 4);
  float4 b0 = *(const float4*)(X + r1), b1 = *(const float4*)(X + r1 + 4);
  uint2 pa0 = pack4bf(a0), pa1 = pack4bf(a1);
  uint2 pb0 = pack4bf(b0), pb1 = pack4bf(b1);
  *(uint4*)(Xb + r0) = make_uint4(pa0.x, pa0.y, pa1.x, pa1.y);
  *(uint4*)(Xb + r1) = make_uint4(pb0.x, pb0.y, pb1.x, pb1.y);
  float4 s0, s1;
  s0.x = 0.5f * (a0.x + b0.x); s0.y = 0.5f * (a0.y + b0.y);
  s0.z = 0.5f * (a0.z + b0.z); s0.w = 0.5f * (a0.w + b0.w);
  s1.x = 0.5f * (a1.x + b1.x); s1.y = 0.5f * (a1.y + b1.y);
  s1.z = 0.5f * (a1.z + b1.z); s1.w = 0.5f * (a1.w + b1.w);
  uint2 q0 = pack4bf(s0), q1 = pack4bf(s1);
  *(uint4*)(Xp + (size_t)row * C_ + c8 * 8) = make_uint4(q0.x, q0.y, q1.x, q1.y);
}

// ---------------- shared GEMM core: 128x128 tile, BK=32, K=512 ----------------
// T2-style bank swizzle (m104-compliant): LDS linear for global_load_lds; the
// per-lane GLOBAL source quarter is swizzled and the fragment READ applies the
// same involution. Measured r25: conflicts ~0, GEMM section ~5 us faster.
__device__ __forceinline__ void gemm_core(const short* __restrict__ A,
                                          const short* __restrict__ Bm,
                                          long r0, long o0,
                                          short* As, short* Bs,
                                          f32x4 (&acc)[4][4]) {
  const int tid  = threadIdx.x;
  const int w    = tid >> 6;
  const int lane = tid & 63;
  const int g    = lane >> 4;
  const int c0   = lane & 15;
  const int wr   = w >> 1;
  const int wc   = w & 1;
  const int srow = lane >> 2;
  const int scol = (((lane & 3) ^ ((lane >> 3) & 3)) * 8);   // swizzled source quarter
  const int gs   = g ^ ((c0 >> 1) & 3);                      // swizzled read quarter

  for (int kk = 0; kk < 16; ++kk) {
    __syncthreads();
#pragma unroll
    for (int i = 0; i < 2; ++i) {
      int arow = i * 64 + w * 16;
      gl_lds16(A  + (r0 + arow + srow) * KK_ + kk * 32 + scol, &As[arow * 32]);
      gl_lds16(Bm + (o0 + arow + srow) * KK_ + kk * 32 + scol, &Bs[arow * 32]);
    }
    __syncthreads();
    bf16x8 a[4], b[4];
#pragma unroll
    for (int m = 0; m < 4; ++m) a[m] = *(const bf16x8*)&As[(wr * 64 + m * 16 + c0) * 32 + gs * 8];
#pragma unroll
    for (int n = 0; n < 4; ++n) b[n] = *(const bf16x8*)&Bs[(wc * 64 + n * 16 + c0) * 32 + gs * 8];
#pragma unroll
    for (int m = 0; m < 4; ++m)
#pragma unroll
      for (int n = 0; n < 4; ++n) acc[m][n] = MFMA16(a[m], b[n], acc[m][n]);
  }
}

// ---------------- MFMA bf16 GEMM: Y = X(R,512) * W(O,512)^T + b ----------------
template<int OUT_BF16, int ROWS, int NBX>
__global__ __launch_bounds__(256) void gemm_mfma(const short* __restrict__ A,
                                                 const short* __restrict__ Bm,
                                                 const float* __restrict__ bias,
                                                 void* __restrict__ Yv,
                                                 int O, float oscale) {
  __shared__ short As[128 * 32];
  __shared__ short Bs[128 * 32];
  const int tid  = threadIdx.x;
  const int w    = tid >> 6;
  const int lane = tid & 63;
  const int g    = lane >> 4;
  const int c0   = lane & 15;
  const int wr   = w >> 1;
  const int wc   = w & 1;
  int rowb, bx;
  xcd_decode<ROWS, NBX>(blockIdx.x, rowb, bx);
  const long r0 = (long)rowb * 128;
  const long o0 = (long)bx * 128;

  f32x4 acc[4][4];
#pragma unroll
  for (int m = 0; m < 4; ++m)
#pragma unroll
    for (int n = 0; n < 4; ++n) acc[m][n] = (f32x4){0.f, 0.f, 0.f, 0.f};

  gemm_core(A, Bm, r0, o0, As, Bs, acc);

#pragma unroll
  for (int m = 0; m < 4; ++m) {
    long row = r0 + wr * 64 + m * 16 + g * 4;
#pragma unroll
    for (int n = 0; n < 4; ++n) {
      long col = o0 + wc * 64 + n * 16 + c0;
      float bv = bias[col];
#pragma unroll
      for (int r = 0; r < 4; ++r) {
        float v = (acc[m][n][r] + bv) * oscale;
        if (OUT_BF16) ((short*)Yv)[(row + r) * O + col] = f2bf(v);
        else          ((float*)Yv)[(row + r) * O + col] = v;
      }
    }
  }
}

// ---------------- fused launch: q+kv projection (1500 blocks) + pooled Wc GEMM (256 blocks) ----------------
__global__ __launch_bounds__(256) void gemm_qkv_wc(const short* __restrict__ xb,
                                                   const short* __restrict__ Wqkvb,
                                                   const float* __restrict__ bq,
                                                   const float* __restrict__ bkv,
                                                   short* __restrict__ Yq,
                                                   short* __restrict__ Ykv,
                                                   const short* __restrict__ xpb,
                                                   const short* __restrict__ Wcb,
                                                   const float* __restrict__ bc,
                                                   float* __restrict__ xc) {
  __shared__ short As[128 * 32];
  __shared__ short Bs[128 * 32];
  const int tid  = threadIdx.x;
  const int w    = tid >> 6;
  const int lane = tid & 63;
  const int g    = lane >> 4;
  const int c0   = lane & 15;
  const int wr   = w >> 1;
  const int wc   = w & 1;

  f32x4 acc[4][4];
#pragma unroll
  for (int m = 0; m < 4; ++m)
#pragma unroll
    for (int n = 0; n < 4; ++n) acc[m][n] = (f32x4){0.f, 0.f, 0.f, 0.f};

  const int blk = blockIdx.x;
  if (blk < 1500) {                       // qkv: 125 rows x 12 cols, XCD-swizzled
    int rowb, bx;
    xcd_decode<125, 12>(blk, rowb, bx);
    const long r0 = (long)rowb * 128;
    const long o0 = (long)bx * 128;
    gemm_core(xb, Wqkvb, r0, o0, As, Bs, acc);
    const bool isq = (bx < 4);
#pragma unroll
    for (int m = 0; m < 4; ++m) {
      long row = r0 + wr * 64 + m * 16 + g * 4;
#pragma unroll
      for (int n = 0; n < 4; ++n) {
        long col = o0 + wc * 64 + n * 16 + c0;
        if (isq) {
          float bv = bq[col];
#pragma unroll
          for (int r = 0; r < 4; ++r)
            Yq[(row + r) * 512 + col] = f2bf((acc[m][n][r] + bv) * QSC_);
        } else {
          long ck = col - 512;
          float bv = bkv[ck];
#pragma unroll
          for (int r = 0; r < 4; ++r)
            Ykv[(row + r) * 1024 + ck] = f2bf(acc[m][n][r] + bv);
        }
      }
    }
  } else {                                // pooled Wc: 64 rows x 4 cols, XCD-swizzled
    int rowb, bx;
    xcd_decode<64, 4>(blk - 1500, rowb, bx);
    const long r0 = (long)rowb * 128;
    const long o0 = (long)bx * 128;
    gemm_core(xpb, Wcb, r0, o0, As, Bs, acc);
#pragma unroll
    for (int m = 0; m < 4; ++m) {
      long row = r0 + wr * 64 + m * 16 + g * 4;
#pragma unroll
      for (int n = 0; n < 4; ++n) {
        long col = o0 + wc * 64 + n * 16 + c0;
        float bv = bc[col];
#pragma unroll
        for (int r = 0; r < 4; ++r)
          xc[(row + r) * 512 + col] = acc[m][n][r] + bv;
      }
    }
  }
}

// LayerNorm + exact GELU: fp32 in -> bf16 out, rows of 512
__global__ __launch_bounds__(256) void ln_gelu(const float* __restrict__ Xc,
                                               short* __restrict__ Xo,
                                               const float* __restrict__ gam,
                                               const float* __restrict__ bet) {
  const int row = blockIdx.x;
  const float* p = Xc + (size_t)row * C_;
  const int t = threadIdx.x;
  float v0 = p[t], v1 = p[t + 256];
  float s  = wave_sum(v0 + v1);
  float ss = wave_sum(v0 * v0 + v1 * v1);
  __shared__ float rs[4], rss[4];
  const int w = t >> 6, lane = t & 63;
  if (lane == 0) { rs[w] = s; rss[w] = ss; }
  __syncthreads();
  float ts  = rs[0] + rs[1] + rs[2] + rs[3];
  float tss = rss[0] + rss[1] + rss[2] + rss[3];
  float mean = ts * (1.0f / C_);
  float var  = tss * (1.0f / C_) - mean * mean;
  float rstd = rsqrtf(var + LN_EPS_);
  float u0 = (v0 - mean) * rstd * gam[t]       + bet[t];
  float u1 = (v1 - mean) * rstd * gam[t + 256] + bet[t + 256];
  Xo[(size_t)row * C_ + t]       = f2bf(u0 * 0.5f * (1.0f + erff(u0 * 0.70710678118654752f)));
  Xo[(size_t)row * C_ + t + 256] = f2bf(u1 * 0.5f * (1.0f + erff(u1 * 0.70710678118654752f)));
}

// ---------------- 32x32 swapped-operand MFMA flash attention (r24 proven form) ----------------
// Fixed-reference softmax (m == 0), VALU l-sum (4-way partials + 1 shfl).
// MODE: 0 pooled, 1 local window, 2 pooled tail.
template<int MODE>
__device__ __forceinline__ void tile32(const short* Ksb, const short* Vtb,
                                       const bf16x8 qf[4],
                                       float& l_c, f32x16* o,
                                       int c, int hi, int koff)
{
  f32x16 sblk[2];
  __builtin_amdgcn_s_setprio(1);
#pragma unroll
  for (int kb = 0; kb < 2; ++kb) {
    f32x16 acc = {};
#pragma unroll
    for (int sl = 0; sl < 4; ++sl) {
      bf16x8 kf = *(const bf16x8*)&Ksb[(kb*32 + c)*KSTR2 + sl*16 + hi*8];
      acc = MFMA32(kf, qf[sl], acc);
    }
    sblk[kb] = acc;
  }
  __builtin_amdgcn_s_setprio(0);

  if (MODE == 1) {
#pragma unroll
    for (int kb = 0; kb < 2; ++kb)
#pragma unroll
      for (int r = 0; r < 16; ++r) {
        int ku = koff + kb*32 + ((r & 3) + 8*(r >> 2));
        if ((unsigned)ku >= 5u) sblk[kb][r] = -3.0e38f;
      }
  }
  if (MODE == 2) {
#pragma unroll
    for (int r = 4; r < 16; ++r) sblk[1][r] = -3.0e38f;   // keys 1000..1023
  }

  float rs4[4] = {0.f, 0.f, 0.f, 0.f};
  int dw[2][8];
#pragma unroll
  for (int kb = 0; kb < 2; ++kb)
#pragma unroll
    for (int i = 0; i < 8; ++i) {
      float p0 = exp2f(sblk[kb][2*i]);
      float p1 = exp2f(sblk[kb][2*i + 1]);
      rs4[i & 3] += p0 + p1;
      int d;
      asm("v_cvt_pk_bf16_f32 %0, %1, %2" : "=v"(d) : "v"(p0), "v"(p1));
      dw[kb][i] = d;
    }
  float rs = (rs4[0] + rs4[1]) + (rs4[2] + rs4[3]);
  rs += __shfl_xor(rs, 32);
  l_c += rs;

  bf16x8 pfrag[2][2];
#pragma unroll
  for (int kb = 0; kb < 2; ++kb)
#pragma unroll
    for (int kp = 0; kp < 2; ++kp) {
      union { int i[4]; bf16x8 v; } u;
      u.i[0] = dw[kb][kp*4 + 0];
      u.i[1] = dw[kb][kp*4 + 1];
      u.i[2] = dw[kb][kp*4 + 2];
      u.i[3] = dw[kb][kp*4 + 3];
      pfrag[kb][kp] = u.v;
    }

  __builtin_amdgcn_s_setprio(1);
#pragma unroll
  for (int db = 0; db < 2; ++db)
#pragma unroll
    for (int kb = 0; kb < 2; ++kb)
#pragma unroll
      for (int kp = 0; kp < 2; ++kp) {
        bf16x8 vf = *(const bf16x8*)&Vtb[(db*32 + c)*KSTR2 + kb*32 + kp*16 + hi*8];
        o[db] = MFMA32(vf, pfrag[kb][kp], o[db]);
      }
  __builtin_amdgcn_s_setprio(0);
}

// Block = 512 thr (8 waves x 32 q = 256 q). 8 chunks per (b,h). Grid 512.
// Staging split: waves 0-3 load K, waves 4-7 load V. LDS-only barriers.
__global__ __launch_bounds__(512, 4) void attn_mfma32(const short* __restrict__ Q,
                                                      const short* __restrict__ KV,
                                                      const short* __restrict__ KVP,
                                                      short* __restrict__ Oa) {
  __shared__ __align__(16) short Ks[2][64 * KSTR2];
  __shared__ __align__(16) short Vt[2][64 * KSTR2];

  const int bid   = blockIdx.x;
  const int bh    = bid & 63;          // XCD-aware decode
  const int chunk = bid >> 6;
  const int b     = bh >> 3;
  const int h     = bh & 7;
  const int n0    = chunk * TQ_;
  const int tid  = threadIdx.x;
  const int wq   = tid >> 6;           // 0..7
  const int lane = tid & 63;
  const int c    = lane & 31;
  const int hi   = lane >> 5;

  const int qabs = n0 + wq * 32 + c;   // absolute query index, <= 2047
  const size_t qrow = (size_t)(b * N_ + qabs) * C_ + h * HD_;
  bf16x8 qf[4];
#pragma unroll
  for (int sl = 0; sl < 4; ++sl) qf[sl] = *(const bf16x8*)(Q + qrow + sl*16 + hi*8);

  const int qlo = (qabs / 5) * 5;
  const int klo = (n0 / 5) * 5;
  const int wlo = ((n0 + wq*32) / 5) * 5;
  const int whi = ((n0 + wq*32 + 31) / 5) * 5 + 5;

  const bool isK = (tid < 256);
  const int u    = tid & 255;
  const int kkey = u >> 3, kdq = u & 7;
  const int vkp  = u & 31, vdq = (u >> 5) & 7;
  const int svkp = (vkp & ~6) | ((vkp & 2) << 1) | ((vkp & 4) >> 1);
  bf16x8 r0v, r1v;

  auto issue = [&](const short* pb_) {
    if (isK) {
      r0v = *(const bf16x8*)(pb_ + (size_t)kkey        * (2*C_) + h*HD_ + kdq*8);
      r1v = *(const bf16x8*)(pb_ + (size_t)(kkey + 32) * (2*C_) + h*HD_ + kdq*8);
    } else {
      r0v = *(const bf16x8*)(pb_ + (size_t)(2*vkp)     * (2*C_) + C_ + h*HD_ + vdq*8);
      r1v = *(const bf16x8*)(pb_ + (size_t)(2*vkp + 1) * (2*C_) + C_ + h*HD_ + vdq*8);
    }
  };
  auto write = [&](int buf) {
    if (isK) {
      *(bf16x8*)&Ks[buf][kkey * KSTR2 + kdq * 8]        = r0v;
      *(bf16x8*)&Ks[buf][(kkey + 32) * KSTR2 + kdq * 8] = r1v;
    } else {
#pragma unroll
      for (int e = 0; e < 8; ++e) {
        unsigned wv = ((unsigned)(unsigned short)r0v[e]) | (((unsigned)(unsigned short)r1v[e]) << 16);
        *(unsigned*)&Vt[buf][(vdq*8 + e) * KSTR2 + 2*svkp] = wv;
      }
    }
  };

  const short* kvloc = KV  + (size_t)(b * N_ + klo) * (2*C_);
  const short* kvp_b = KVP + (size_t)(b * M_)       * (2*C_);

  float l_c = 0.f;
  f32x16 o[2];
  o[0] = (f32x16){}; o[1] = (f32x16){};

  issue(kvloc);
  write(0);
  lds_barrier();
  int cur = 0;

#pragma unroll 1
  for (int t = 0; t < LT_; ++t) {          // local tiles (absolute keys klo+64t)
    const short* nxt = (t < LT_ - 1) ? kvloc + (size_t)(t + 1) * 64 * (2*C_) : kvp_b;
    issue(nxt);
    const int base = klo + t * 64;
    if (base < whi && base + 64 > wlo)
      tile32<1>(Ks[cur], Vt[cur], qf, l_c, o, c, hi, base + 4*hi - qlo);
    write(cur ^ 1);
    lds_barrier();
    cur ^= 1;
  }
#pragma unroll 1
  for (int t = 0; t < 15; ++t) {           // pooled tiles 0..14 (prefetch 1..15)
    issue(kvp_b + (size_t)(t + 1) * 64 * (2*C_));
    tile32<0>(Ks[cur], Vt[cur], qf, l_c, o, c, hi, 0);
    write(cur ^ 1);
    lds_barrier();
    cur ^= 1;
  }
  tile32<2>(Ks[cur], Vt[cur], qf, l_c, o, c, hi, 0);  // pooled tail (40 keys)

  if (qabs < N_) {
    float inv = 1.0f / l_c;
    short* orow = Oa + ((size_t)(b * N_ + qabs)) * C_ + h * HD_;
#pragma unroll
    for (int db = 0; db < 2; ++db)
#pragma unroll
      for (int rq = 0; rq < 4; ++rq) {
        short4v sv;
#pragma unroll
        for (int i = 0; i < 4; ++i) sv[i] = f2bf(o[db][rq*4 + i] * inv);
        *(short4v*)(orow + db*32 + rq*8 + 4*hi) = sv;
      }
  }
}

extern "C" void kernel_launch(void* const* d_in, const int* in_sizes, int n_in,
                              void* d_out, int out_size, void* d_ws, size_t ws_size,
                              hipStream_t stream) {
  const float* x   = (const float*)d_in[0];
  const float* Wq  = (const float*)d_in[1];
  const float* bq  = (const float*)d_in[2];
  const float* Wkv = (const float*)d_in[3];
  const float* bkv = (const float*)d_in[4];
  const float* Wc  = (const float*)d_in[5];
  const float* bc  = (const float*)d_in[6];
  const float* lng = (const float*)d_in[7];
  const float* lnb = (const float*)d_in[8];
  const float* Wp  = (const float*)d_in[9];
  const float* bp  = (const float*)d_in[10];
  float* out = (float*)d_out;

  // workspace layout: fp32 region first, then bf16 regions (all 16B aligned)
  float* xc   = (float*)d_ws;                         // RP_*512 fp32
  short* sb   = (short*)(xc + (size_t)RP_ * 512);
  short* xb    = sb;                                  // 16000*512
  short* qb    = xb   + (size_t)16000 * 512;          // NPAD_*512 (pre-scaled, log2-domain)
  short* kvb   = qb   + (size_t)NPAD_ * 512;          // NPAD_*1024
  short* xpb   = kvb  + (size_t)NPAD_ * 1024;         // RP_*512
  short* xcb   = xpb  + (size_t)RP_ * 512;            // RP_*512
  short* kvpb  = xcb  + (size_t)RP_ * 512;            // RP_*1024
  short* aoutb = kvpb + (size_t)RP_ * 1024;           // 16000*512
  short* Wqkvb = aoutb + (size_t)16000 * 512;         // 1536*512 (q rows 0..511, kv rows 512..1535)
  short* Wcb   = Wqkvb + (size_t)1536 * 512;          // 512*512
  short* Wpb   = Wcb  + (size_t)512 * 512;            // 512*512

  dim3 blk(256);

  // converts + fused pool (weights in ONE launch)
  cvt_pool<<<dim3((B_*M_*(C_/8) + 255)/256), blk, 0, stream>>>(x, xb, xpb);
  cvt_all<<<dim3((2560*512/8 + 255)/256), blk, 0, stream>>>(Wq, Wkv, Wc, Wp, Wqkvb, Wcb, Wpb);

  // fused launch: q+kv projection + pooled Wc GEMM (both XCD-swizzled)
  gemm_qkv_wc<<<dim3(1756), blk, 0, stream>>>(xb, Wqkvb, bq, bkv, qb, kvb,
                                              xpb, Wcb, bc, xc);

  // pooled pre-path tail
  ln_gelu<<<dim3(B_ * M_), blk, 0, stream>>>(xc, xcb, lng, lnb);
  gemm_mfma<1, 64, 8><<<dim3(512), blk, 0, stream>>>(xcb, Wqkvb + 512*512, bkv, kvpb, 2*C_, 1.0f);

  // fused attention: 8-wave blocks, fixed-reference softmax, LDS-only barriers
  attn_mfma32<<<dim3(64 * NCH_), dim3(512), 0, stream>>>(qb, kvb, kvpb, aoutb);

  // output projection (fp32 out, XCD-swizzled; O=512 -> 4 column tiles)
  gemm_mfma<0, 125, 4><<<dim3(500), blk, 0, stream>>>(aoutb, Wpb, bp, out, C_, 1.0f);
}

// Round 30
// 160.279 us; speedup vs baseline: 1.0563x; 1.0111x over previous
//
#include <hip/hip_runtime.h>
#include <hip/hip_bf16.h>
#include <math.h>

// Problem constants
#define B_   8
#define N_   2000
#define C_   512
#define H_   8
#define W_   5
#define SR_  2
#define M_   1000      // N/SR
#define HD_  64        // C/H
#define KK_  512       // shared inner dim of every projection
#define RP_  8192      // padded row count for pooled path (8000 -> 8192)
#define NPAD_ 16384    // padded row count for q/kv buffers
#define LN_EPS_ 1e-5f
#define SCALE_  0.125f             // hd^-0.5
#define QSC_    0.18033688011112042f  // SCALE_ * log2(e): QK scores in log2 domain

// attention tiling (32x32 swapped-operand structure, 8-wave blocks) -- proven config
#define TQ_   256      // q rows per block: 8 waves x 32 queries
#define NCH_  8        // chunks per (b,h)
#define LT_   5        // local tiles per chunk
#define KSTR2 72       // LDS row stride in bf16: 144B rows, single b128 access, 0 conflicts

typedef __attribute__((ext_vector_type(8))) short bf16x8;
typedef __attribute__((ext_vector_type(4))) short short4v;
typedef __attribute__((ext_vector_type(4))) float f32x4;
typedef __attribute__((ext_vector_type(16))) float f32x16;
#define MFMA16(a,b,c) __builtin_amdgcn_mfma_f32_16x16x32_bf16(a,b,c,0,0,0)
#define MFMA32(a,b,c) __builtin_amdgcn_mfma_f32_32x32x16_bf16(a,b,c,0,0,0)

// LDS-only barrier (r27: neutral vs __syncthreads, kept -- never worse).
__device__ __forceinline__ void lds_barrier() {
  asm volatile("s_waitcnt lgkmcnt(0)" ::: "memory");
  __builtin_amdgcn_s_barrier();
}

__device__ __forceinline__ short f2bf(float f) {
  unsigned u = __float_as_uint(f);
  u += 0x7FFFu + ((u >> 16) & 1u);
  return (short)(u >> 16);
}
__device__ __forceinline__ uint2 pack4bf(float4 v) {
  unsigned a = ((unsigned)(unsigned short)f2bf(v.x)) | (((unsigned)(unsigned short)f2bf(v.y)) << 16);
  unsigned b = ((unsigned)(unsigned short)f2bf(v.z)) | (((unsigned)(unsigned short)f2bf(v.w)) << 16);
  return make_uint2(a, b);
}

__device__ __forceinline__ float wave_sum(float v) {
#pragma unroll
  for (int o = 32; o > 0; o >>= 1) v += __shfl_xor(v, o);
  return v;
}

__device__ __forceinline__ void gl_lds16(const void* g, void* l) {
  __builtin_amdgcn_global_load_lds(
      (const __attribute__((address_space(1))) void*)g,
      (__attribute__((address_space(3))) void*)l, 16, 0, 0);
}

// XCD-aware decode for a ROWS x NBX tile grid launched 1D.
// Bijective (exact tail handling for ROWS % 8 != 0). NBX must equal O/128.
template<int ROWS, int NBX>
__device__ __forceinline__ void xcd_decode(int b, int& row, int& bx) {
  constexpr int GROUP = 8 * NBX;
  constexpr int FULL  = (ROWS / 8) * GROUP;
  constexpr int REM   = ROWS % 8;
  if (b < FULL) {
    row = 8 * (b / GROUP) + (b & 7);
    bx  = (b % GROUP) >> 3;
  } else {
    int b2 = b - FULL;
    row = (ROWS - REM) + (REM ? b2 % (REM ? REM : 1) : 0);
    bx  = REM ? b2 / REM : 0;
  }
}

// ---------------- fused converts: x->bf16 + pair-mean pool (blocks 0..1999)
//                  + ALL weight converts (blocks 2000..2639) in ONE launch ----------------
__global__ __launch_bounds__(256) void cvt_fused(const float* __restrict__ X,
                                                 short* __restrict__ Xb,
                                                 short* __restrict__ Xp,
                                                 const float* __restrict__ Wq,
                                                 const float* __restrict__ Wkv,
                                                 const float* __restrict__ Wc,
                                                 const float* __restrict__ Wp,
                                                 short* __restrict__ Wqkvb,
                                                 short* __restrict__ Wcb,
                                                 short* __restrict__ Wpb) {
  const int blk = blockIdx.x;
  if (blk < 2000) {                      // pool path: 512000 items
    int idx = blk * 256 + threadIdx.x;
    int row = idx / (C_ / 8);            // pooled row
    int c8  = idx % (C_ / 8);
    int b = row / M_, m = row % M_;
    size_t r0 = ((size_t)b * N_ + 2 * m) * C_ + c8 * 8;
    size_t r1 = r0 + C_;
    float4 a0 = *(const float4*)(X + r0), a1 = *(const float4*)(X + r0 + 4);
    float4 b0 = *(const float4*)(X + r1), b1 = *(const float4*)(X + r1 + 4);
    uint2 pa0 = pack4bf(a0), pa1 = pack4bf(a1);
    uint2 pb0 = pack4bf(b0), pb1 = pack4bf(b1);
    *(uint4*)(Xb + r0) = make_uint4(pa0.x, pa0.y, pa1.x, pa1.y);
    *(uint4*)(Xb + r1) = make_uint4(pb0.x, pb0.y, pb1.x, pb1.y);
    float4 s0, s1;
    s0.x = 0.5f * (a0.x + b0.x); s0.y = 0.5f * (a0.y + b0.y);
    s0.z = 0.5f * (a0.z + b0.z); s0.w = 0.5f * (a0.w + b0.w);
    s1.x = 0.5f * (a1.x + b1.x); s1.y = 0.5f * (a1.y + b1.y);
    s1.z = 0.5f * (a1.z + b1.z); s1.w = 0.5f * (a1.w + b1.w);
    uint2 q0 = pack4bf(s0), q1 = pack4bf(s1);
    *(uint4*)(Xp + (size_t)row * C_ + c8 * 8) = make_uint4(q0.x, q0.y, q1.x, q1.y);
  } else {                               // weight converts: 163840 items
    int i = (blk - 2000) * 256 + threadIdx.x;
    const int nq = 512*512/8, nkv = 1024*512/8, nc = 512*512/8, np = 512*512/8;
    if (i >= nq + nkv + nc + np) return;
    const float* src; short* dst; int off;
    if (i < nq)                { src = Wq;  dst = Wqkvb;             off = i; }
    else if (i < nq + nkv)     { src = Wkv; dst = Wqkvb + 512*512;   off = i - nq; }
    else if (i < nq + nkv + nc){ src = Wc;  dst = Wcb;               off = i - nq - nkv; }
    else                       { src = Wp;  dst = Wpb;               off = i - nq - nkv - nc; }
    float4 a = reinterpret_cast<const float4*>(src)[off * 2];
    float4 b = reinterpret_cast<const float4*>(src)[off * 2 + 1];
    uint2 pa = pack4bf(a), pb = pack4bf(b);
    reinterpret_cast<uint4*>(dst)[off] = make_uint4(pa.x, pa.y, pb.x, pb.y);
  }
}

// ---------------- shared GEMM core: 128x128 tile, BK=32, K=512 ----------------
// T2-style bank swizzle (m104-compliant): LDS linear for global_load_lds; the
// per-lane GLOBAL source quarter is swizzled and the fragment READ applies the
// same involution. Measured r25: conflicts ~0, GEMM section ~5 us faster.
__device__ __forceinline__ void gemm_core(const short* __restrict__ A,
                                          const short* __restrict__ Bm,
                                          long r0, long o0,
                                          short* As, short* Bs,
                                          f32x4 (&acc)[4][4]) {
  const int tid  = threadIdx.x;
  const int w    = tid >> 6;
  const int lane = tid & 63;
  const int g    = lane >> 4;
  const int c0   = lane & 15;
  const int wr   = w >> 1;
  const int wc   = w & 1;
  const int srow = lane >> 2;
  const int scol = (((lane & 3) ^ ((lane >> 3) & 3)) * 8);   // swizzled source quarter
  const int gs   = g ^ ((c0 >> 1) & 3);                      // swizzled read quarter

  for (int kk = 0; kk < 16; ++kk) {
    __syncthreads();
#pragma unroll
    for (int i = 0; i < 2; ++i) {
      int arow = i * 64 + w * 16;
      gl_lds16(A  + (r0 + arow + srow) * KK_ + kk * 32 + scol, &As[arow * 32]);
      gl_lds16(Bm + (o0 + arow + srow) * KK_ + kk * 32 + scol, &Bs[arow * 32]);
    }
    __syncthreads();
    bf16x8 a[4], b[4];
#pragma unroll
    for (int m = 0; m < 4; ++m) a[m] = *(const bf16x8*)&As[(wr * 64 + m * 16 + c0) * 32 + gs * 8];
#pragma unroll
    for (int n = 0; n < 4; ++n) b[n] = *(const bf16x8*)&Bs[(wc * 64 + n * 16 + c0) * 32 + gs * 8];
#pragma unroll
    for (int m = 0; m < 4; ++m)
#pragma unroll
      for (int n = 0; n < 4; ++n) acc[m][n] = MFMA16(a[m], b[n], acc[m][n]);
  }
}

// ---------------- MFMA bf16 GEMM: Y = X(R,512) * W(O,512)^T + b ----------------
template<int OUT_BF16, int ROWS, int NBX>
__global__ __launch_bounds__(256) void gemm_mfma(const short* __restrict__ A,
                                                 const short* __restrict__ Bm,
                                                 const float* __restrict__ bias,
                                                 void* __restrict__ Yv,
                                                 int O, float oscale) {
  __shared__ short As[128 * 32];
  __shared__ short Bs[128 * 32];
  const int tid  = threadIdx.x;
  const int w    = tid >> 6;
  const int lane = tid & 63;
  const int g    = lane >> 4;
  const int c0   = lane & 15;
  const int wr   = w >> 1;
  const int wc   = w & 1;
  int rowb, bx;
  xcd_decode<ROWS, NBX>(blockIdx.x, rowb, bx);
  const long r0 = (long)rowb * 128;
  const long o0 = (long)bx * 128;

  f32x4 acc[4][4];
#pragma unroll
  for (int m = 0; m < 4; ++m)
#pragma unroll
    for (int n = 0; n < 4; ++n) acc[m][n] = (f32x4){0.f, 0.f, 0.f, 0.f};

  gemm_core(A, Bm, r0, o0, As, Bs, acc);

#pragma unroll
  for (int m = 0; m < 4; ++m) {
    long row = r0 + wr * 64 + m * 16 + g * 4;
#pragma unroll
    for (int n = 0; n < 4; ++n) {
      long col = o0 + wc * 64 + n * 16 + c0;
      float bv = bias[col];
#pragma unroll
      for (int r = 0; r < 4; ++r) {
        float v = (acc[m][n][r] + bv) * oscale;
        if (OUT_BF16) ((short*)Yv)[(row + r) * O + col] = f2bf(v);
        else          ((float*)Yv)[(row + r) * O + col] = v;
      }
    }
  }
}

// ---------------- fused launch: q+kv projection (1500 blocks) + pooled Wc GEMM (256 blocks) ----------------
__global__ __launch_bounds__(256) void gemm_qkv_wc(const short* __restrict__ xb,
                                                   const short* __restrict__ Wqkvb,
                                                   const float* __restrict__ bq,
                                                   const float* __restrict__ bkv,
                                                   short* __restrict__ Yq,
                                                   short* __restrict__ Ykv,
                                                   const short* __restrict__ xpb,
                                                   const short* __restrict__ Wcb,
                                                   const float* __restrict__ bc,
                                                   float* __restrict__ xc) {
  __shared__ short As[128 * 32];
  __shared__ short Bs[128 * 32];
  const int tid  = threadIdx.x;
  const int w    = tid >> 6;
  const int lane = tid & 63;
  const int g    = lane >> 4;
  const int c0   = lane & 15;
  const int wr   = w >> 1;
  const int wc   = w & 1;

  f32x4 acc[4][4];
#pragma unroll
  for (int m = 0; m < 4; ++m)
#pragma unroll
    for (int n = 0; n < 4; ++n) acc[m][n] = (f32x4){0.f, 0.f, 0.f, 0.f};

  const int blk = blockIdx.x;
  if (blk < 1500) {                       // qkv: 125 rows x 12 cols, XCD-swizzled
    int rowb, bx;
    xcd_decode<125, 12>(blk, rowb, bx);
    const long r0 = (long)rowb * 128;
    const long o0 = (long)bx * 128;
    gemm_core(xb, Wqkvb, r0, o0, As, Bs, acc);
    const bool isq = (bx < 4);
#pragma unroll
    for (int m = 0; m < 4; ++m) {
      long row = r0 + wr * 64 + m * 16 + g * 4;
#pragma unroll
      for (int n = 0; n < 4; ++n) {
        long col = o0 + wc * 64 + n * 16 + c0;
        if (isq) {
          float bv = bq[col];
#pragma unroll
          for (int r = 0; r < 4; ++r)
            Yq[(row + r) * 512 + col] = f2bf((acc[m][n][r] + bv) * QSC_);
        } else {
          long ck = col - 512;
          float bv = bkv[ck];
#pragma unroll
          for (int r = 0; r < 4; ++r)
            Ykv[(row + r) * 1024 + ck] = f2bf(acc[m][n][r] + bv);
        }
      }
    }
  } else {                                // pooled Wc: 64 rows x 4 cols, XCD-swizzled
    int rowb, bx;
    xcd_decode<64, 4>(blk - 1500, rowb, bx);
    const long r0 = (long)rowb * 128;
    const long o0 = (long)bx * 128;
    gemm_core(xpb, Wcb, r0, o0, As, Bs, acc);
#pragma unroll
    for (int m = 0; m < 4; ++m) {
      long row = r0 + wr * 64 + m * 16 + g * 4;
#pragma unroll
      for (int n = 0; n < 4; ++n) {
        long col = o0 + wc * 64 + n * 16 + c0;
        float bv = bc[col];
#pragma unroll
        for (int r = 0; r < 4; ++r)
          xc[(row + r) * 512 + col] = acc[m][n][r] + bv;
      }
    }
  }
}

// LayerNorm + exact GELU: fp32 in -> bf16 out, rows of 512
__global__ __launch_bounds__(256) void ln_gelu(const float* __restrict__ Xc,
                                               short* __restrict__ Xo,
                                               const float* __restrict__ gam,
                                               const float* __restrict__ bet) {
  const int row = blockIdx.x;
  const float* p = Xc + (size_t)row * C_;
  const int t = threadIdx.x;
  float v0 = p[t], v1 = p[t + 256];
  float s  = wave_sum(v0 + v1);
  float ss = wave_sum(v0 * v0 + v1 * v1);
  __shared__ float rs[4], rss[4];
  const int w = t >> 6, lane = t & 63;
  if (lane == 0) { rs[w] = s; rss[w] = ss; }
  __syncthreads();
  float ts  = rs[0] + rs[1] + rs[2] + rs[3];
  float tss = rss[0] + rss[1] + rss[2] + rss[3];
  float mean = ts * (1.0f / C_);
  float var  = tss * (1.0f / C_) - mean * mean;
  float rstd = rsqrtf(var + LN_EPS_);
  float u0 = (v0 - mean) * rstd * gam[t]       + bet[t];
  float u1 = (v1 - mean) * rstd * gam[t + 256] + bet[t + 256];
  Xo[(size_t)row * C_ + t]       = f2bf(u0 * 0.5f * (1.0f + erff(u0 * 0.70710678118654752f)));
  Xo[(size_t)row * C_ + t + 256] = f2bf(u1 * 0.5f * (1.0f + erff(u1 * 0.70710678118654752f)));
}

// ---------------- 32x32 swapped-operand MFMA flash attention (r24 proven form) ----------------
// Fixed-reference softmax (m == 0), VALU l-sum (4-way partials + 1 shfl).
// MODE: 0 pooled, 1 local window, 2 pooled tail.
template<int MODE>
__device__ __forceinline__ void tile32(const short* Ksb, const short* Vtb,
                                       const bf16x8 qf[4],
                                       float& l_c, f32x16* o,
                                       int c, int hi, int koff)
{
  f32x16 sblk[2];
  __builtin_amdgcn_s_setprio(1);
#pragma unroll
  for (int kb = 0; kb < 2; ++kb) {
    f32x16 acc = {};
#pragma unroll
    for (int sl = 0; sl < 4; ++sl) {
      bf16x8 kf = *(const bf16x8*)&Ksb[(kb*32 + c)*KSTR2 + sl*16 + hi*8];
      acc = MFMA32(kf, qf[sl], acc);
    }
    sblk[kb] = acc;
  }
  __builtin_amdgcn_s_setprio(0);

  if (MODE == 1) {
#pragma unroll
    for (int kb = 0; kb < 2; ++kb)
#pragma unroll
      for (int r = 0; r < 16; ++r) {
        int ku = koff + kb*32 + ((r & 3) + 8*(r >> 2));
        if ((unsigned)ku >= 5u) sblk[kb][r] = -3.0e38f;
      }
  }
  if (MODE == 2) {
#pragma unroll
    for (int r = 4; r < 16; ++r) sblk[1][r] = -3.0e38f;   // keys 1000..1023
  }

  float rs4[4] = {0.f, 0.f, 0.f, 0.f};
  int dw[2][8];
#pragma unroll
  for (int kb = 0; kb < 2; ++kb)
#pragma unroll
    for (int i = 0; i < 8; ++i) {
      float p0 = exp2f(sblk[kb][2*i]);
      float p1 = exp2f(sblk[kb][2*i + 1]);
      rs4[i & 3] += p0 + p1;
      int d;
      asm("v_cvt_pk_bf16_f32 %0, %1, %2" : "=v"(d) : "v"(p0), "v"(p1));
      dw[kb][i] = d;
    }
  float rs = (rs4[0] + rs4[1]) + (rs4[2] + rs4[3]);
  rs += __shfl_xor(rs, 32);
  l_c += rs;

  bf16x8 pfrag[2][2];
#pragma unroll
  for (int kb = 0; kb < 2; ++kb)
#pragma unroll
    for (int kp = 0; kp < 2; ++kp) {
      union { int i[4]; bf16x8 v; } u;
      u.i[0] = dw[kb][kp*4 + 0];
      u.i[1] = dw[kb][kp*4 + 1];
      u.i[2] = dw[kb][kp*4 + 2];
      u.i[3] = dw[kb][kp*4 + 3];
      pfrag[kb][kp] = u.v;
    }

  __builtin_amdgcn_s_setprio(1);
#pragma unroll
  for (int db = 0; db < 2; ++db)
#pragma unroll
    for (int kb = 0; kb < 2; ++kb)
#pragma unroll
      for (int kp = 0; kp < 2; ++kp) {
        bf16x8 vf = *(const bf16x8*)&Vtb[(db*32 + c)*KSTR2 + kb*32 + kp*16 + hi*8];
        o[db] = MFMA32(vf, pfrag[kb][kp], o[db]);
      }
  __builtin_amdgcn_s_setprio(0);
}

// Block = 512 thr (8 waves x 32 q = 256 q). 8 chunks per (b,h). Grid 512.
// Staging split: waves 0-3 load K, waves 4-7 load V. LDS-only barriers.
__global__ __launch_bounds__(512, 4) void attn_mfma32(const short* __restrict__ Q,
                                                      const short* __restrict__ KV,
                                                      const short* __restrict__ KVP,
                                                      short* __restrict__ Oa) {
  __shared__ __align__(16) short Ks[2][64 * KSTR2];
  __shared__ __align__(16) short Vt[2][64 * KSTR2];

  const int bid   = blockIdx.x;
  const int bh    = bid & 63;          // XCD-aware decode
  const int chunk = bid >> 6;
  const int b     = bh >> 3;
  const int h     = bh & 7;
  const int n0    = chunk * TQ_;
  const int tid  = threadIdx.x;
  const int wq   = tid >> 6;           // 0..7
  const int lane = tid & 63;
  const int c    = lane & 31;
  const int hi   = lane >> 5;

  const int qabs = n0 + wq * 32 + c;   // absolute query index, <= 2047
  const size_t qrow = (size_t)(b * N_ + qabs) * C_ + h * HD_;
  bf16x8 qf[4];
#pragma unroll
  for (int sl = 0; sl < 4; ++sl) qf[sl] = *(const bf16x8*)(Q + qrow + sl*16 + hi*8);

  const int qlo = (qabs / 5) * 5;
  const int klo = (n0 / 5) * 5;
  const int wlo = ((n0 + wq*32) / 5) * 5;
  const int whi = ((n0 + wq*32 + 31) / 5) * 5 + 5;

  const bool isK = (tid < 256);
  const int u    = tid & 255;
  const int kkey = u >> 3, kdq = u & 7;
  const int vkp  = u & 31, vdq = (u >> 5) & 7;
  const int svkp = (vkp & ~6) | ((vkp & 2) << 1) | ((vkp & 4) >> 1);
  bf16x8 r0v, r1v;

  auto issue = [&](const short* pb_) {
    if (isK) {
      r0v = *(const bf16x8*)(pb_ + (size_t)kkey        * (2*C_) + h*HD_ + kdq*8);
      r1v = *(const bf16x8*)(pb_ + (size_t)(kkey + 32) * (2*C_) + h*HD_ + kdq*8);
    } else {
      r0v = *(const bf16x8*)(pb_ + (size_t)(2*vkp)     * (2*C_) + C_ + h*HD_ + vdq*8);
      r1v = *(const bf16x8*)(pb_ + (size_t)(2*vkp + 1) * (2*C_) + C_ + h*HD_ + vdq*8);
    }
  };
  auto write = [&](int buf) {
    if (isK) {
      *(bf16x8*)&Ks[buf][kkey * KSTR2 + kdq * 8]        = r0v;
      *(bf16x8*)&Ks[buf][(kkey + 32) * KSTR2 + kdq * 8] = r1v;
    } else {
#pragma unroll
      for (int e = 0; e < 8; ++e) {
        unsigned wv = ((unsigned)(unsigned short)r0v[e]) | (((unsigned)(unsigned short)r1v[e]) << 16);
        *(unsigned*)&Vt[buf][(vdq*8 + e) * KSTR2 + 2*svkp] = wv;
      }
    }
  };

  const short* kvloc = KV  + (size_t)(b * N_ + klo) * (2*C_);
  const short* kvp_b = KVP + (size_t)(b * M_)       * (2*C_);

  float l_c = 0.f;
  f32x16 o[2];
  o[0] = (f32x16){}; o[1] = (f32x16){};

  issue(kvloc);
  write(0);
  lds_barrier();
  int cur = 0;

#pragma unroll 1
  for (int t = 0; t < LT_; ++t) {          // local tiles (absolute keys klo+64t)
    const short* nxt = (t < LT_ - 1) ? kvloc + (size_t)(t + 1) * 64 * (2*C_) : kvp_b;
    issue(nxt);
    const int base = klo + t * 64;
    if (base < whi && base + 64 > wlo)
      tile32<1>(Ks[cur], Vt[cur], qf, l_c, o, c, hi, base + 4*hi - qlo);
    write(cur ^ 1);
    lds_barrier();
    cur ^= 1;
  }
#pragma unroll 1
  for (int t = 0; t < 15; ++t) {           // pooled tiles 0..14 (prefetch 1..15)
    issue(kvp_b + (size_t)(t + 1) * 64 * (2*C_));
    tile32<0>(Ks[cur], Vt[cur], qf, l_c, o, c, hi, 0);
    write(cur ^ 1);
    lds_barrier();
    cur ^= 1;
  }
  tile32<2>(Ks[cur], Vt[cur], qf, l_c, o, c, hi, 0);  // pooled tail (40 keys)

  if (qabs < N_) {
    float inv = 1.0f / l_c;
    short* orow = Oa + ((size_t)(b * N_ + qabs)) * C_ + h * HD_;
#pragma unroll
    for (int db = 0; db < 2; ++db)
#pragma unroll
      for (int rq = 0; rq < 4; ++rq) {
        short4v sv;
#pragma unroll
        for (int i = 0; i < 4; ++i) sv[i] = f2bf(o[db][rq*4 + i] * inv);
        *(short4v*)(orow + db*32 + rq*8 + 4*hi) = sv;
      }
  }
}

extern "C" void kernel_launch(void* const* d_in, const int* in_sizes, int n_in,
                              void* d_out, int out_size, void* d_ws, size_t ws_size,
                              hipStream_t stream) {
  const float* x   = (const float*)d_in[0];
  const float* Wq  = (const float*)d_in[1];
  const float* bq  = (const float*)d_in[2];
  const float* Wkv = (const float*)d_in[3];
  const float* bkv = (const float*)d_in[4];
  const float* Wc  = (const float*)d_in[5];
  const float* bc  = (const float*)d_in[6];
  const float* lng = (const float*)d_in[7];
  const float* lnb = (const float*)d_in[8];
  const float* Wp  = (const float*)d_in[9];
  const float* bp  = (const float*)d_in[10];
  float* out = (float*)d_out;

  // workspace layout: fp32 region first, then bf16 regions (all 16B aligned)
  float* xc   = (float*)d_ws;                         // RP_*512 fp32
  short* sb   = (short*)(xc + (size_t)RP_ * 512);
  short* xb    = sb;                                  // 16000*512
  short* qb    = xb   + (size_t)16000 * 512;          // NPAD_*512 (pre-scaled, log2-domain)
  short* kvb   = qb   + (size_t)NPAD_ * 512;          // NPAD_*1024
  short* xpb   = kvb  + (size_t)NPAD_ * 1024;         // RP_*512
  short* xcb   = xpb  + (size_t)RP_ * 512;            // RP_*512
  short* kvpb  = xcb  + (size_t)RP_ * 512;            // RP_*1024
  short* aoutb = kvpb + (size_t)RP_ * 1024;           // 16000*512
  short* Wqkvb = aoutb + (size_t)16000 * 512;         // 1536*512 (q rows 0..511, kv rows 512..1535)
  short* Wcb   = Wqkvb + (size_t)1536 * 512;          // 512*512
  short* Wpb   = Wcb  + (size_t)512 * 512;            // 512*512

  dim3 blk(256);

  // all converts + pool in ONE launch (2000 pool blocks + 640 weight blocks)
  cvt_fused<<<dim3(2640), blk, 0, stream>>>(x, xb, xpb, Wq, Wkv, Wc, Wp, Wqkvb, Wcb, Wpb);

  // fused launch: q+kv projection + pooled Wc GEMM (both XCD-swizzled)
  gemm_qkv_wc<<<dim3(1756), blk, 0, stream>>>(xb, Wqkvb, bq, bkv, qb, kvb,
                                              xpb, Wcb, bc, xc);

  // pooled pre-path tail
  ln_gelu<<<dim3(B_ * M_), blk, 0, stream>>>(xc, xcb, lng, lnb);
  gemm_mfma<1, 64, 8><<<dim3(512), blk, 0, stream>>>(xcb, Wqkvb + 512*512, bkv, kvpb, 2*C_, 1.0f);

  // fused attention: 8-wave blocks, fixed-reference softmax, LDS-only barriers
  attn_mfma32<<<dim3(64 * NCH_), dim3(512), 0, stream>>>(qb, kvb, kvpb, aoutb);

  // output projection (fp32 out, XCD-swizzled; O=512 -> 4 column tiles)
  gemm_mfma<0, 125, 4><<<dim3(500), blk, 0, stream>>>(aoutb, Wpb, bp, out, C_, 1.0f);
}